// Round 4
// baseline (190.509 us; speedup 1.0000x reference)
//
#include <hip/hip_runtime.h>
#include <hip/hip_bf16.h>
#include <cstddef>
#include <cstdint>

// B=2, S=2048, D=1024, H=16, DH=64, M=B*S=4096
//
// Pipeline (bf16 MFMA 16x16x32, fp32 accum):
//   convert_all: queries/keys/values/Wq/Wk/Wv/Wo -> bf16 (one kernel)
//   packmask:    mask int32 [2048][2048] -> bit-packed u64 [2048][32]
//   qkv_gemm:    qbuf = qin@Wq^T+bq, kbuf = kin@Wk^T+bk, vtb = Wv@vin^T+bv (V^T)
//   attn_mfma:   swapped QK^T (lane owns q-row), fixed-C softmax, PV
//                Q fragments in registers; single-buffered K/V; 6 blocks/CU
//   out_gemm:    out = ctx @ Wo^T + bo (fp32 out)
//
// Double-split_proj algebra: head a of attention reads Q-projection rows
// s = (qrow&127)*16 + a with column block (qrow>>7)*64; K plain; V^T via swapped GEMM.

typedef __attribute__((ext_vector_type(8))) short bf16x8;
typedef __attribute__((ext_vector_type(4))) float f32x4;

__device__ __forceinline__ void gl_lds16(const void* g, void* l) {
    __builtin_amdgcn_global_load_lds(
        (const __attribute__((address_space(1))) void*)g,
        (__attribute__((address_space(3))) void*)l, 16, 0, 0);
}

// ---------------- all fp32->bf16 converts in one kernel ---------------------
__global__ __launch_bounds__(256) void convert_all(
    const float* __restrict__ q, const float* __restrict__ k, const float* __restrict__ v,
    const float* __restrict__ wq, const float* __restrict__ wk,
    const float* __restrict__ wv, const float* __restrict__ wo,
    __hip_bfloat16* __restrict__ dq, __hip_bfloat16* __restrict__ dk,
    __hip_bfloat16* __restrict__ dv, __hip_bfloat16* __restrict__ dwq,
    __hip_bfloat16* __restrict__ dwk, __hip_bfloat16* __restrict__ dwv,
    __hip_bfloat16* __restrict__ dwo)
{
    const int bid = blockIdx.x;
    const float* s; __hip_bfloat16* d; int base;
    if      (bid < 2048) { s = q;  d = dq;  base = bid; }
    else if (bid < 4096) { s = k;  d = dk;  base = bid - 2048; }
    else if (bid < 6144) { s = v;  d = dv;  base = bid - 4096; }
    else if (bid < 6656) { s = wq; d = dwq; base = bid - 6144; }
    else if (bid < 7168) { s = wk; d = dwk; base = bid - 6656; }
    else if (bid < 7680) { s = wv; d = dwv; base = bid - 7168; }
    else                 { s = wo; d = dwo; base = bid - 7680; }
    const size_t i = (size_t)base * 256 + threadIdx.x;
    const float4* sp = (const float4*)s + i * 2;
    float4 v0 = sp[0], v1 = sp[1];
    union { __hip_bfloat16 h[8]; int4 qd; } u;
    u.h[0] = __float2bfloat16(v0.x); u.h[1] = __float2bfloat16(v0.y);
    u.h[2] = __float2bfloat16(v0.z); u.h[3] = __float2bfloat16(v0.w);
    u.h[4] = __float2bfloat16(v1.x); u.h[5] = __float2bfloat16(v1.y);
    u.h[6] = __float2bfloat16(v1.z); u.h[7] = __float2bfloat16(v1.w);
    *((int4*)d + i) = u.qd;
}

// ---------------- mask -> bitmask: mbits[q][w] bit j = mask[q][w*64+j] ------
__global__ __launch_bounds__(256) void packmask(const int* __restrict__ mask,
                                                unsigned long long* __restrict__ mbits)
{
    const int wid  = (blockIdx.x * 256 + threadIdx.x) >> 6;  // 0..65535
    const int lane = threadIdx.x & 63;
    const int qr = wid >> 5, w64 = wid & 31;
    const int m = mask[(size_t)qr * 2048 + w64 * 64 + lane];
    const unsigned long long bal = __ballot(m != 0);
    if (lane == 0) mbits[(size_t)qr * 32 + w64] = bal;
}

// ---------------- shared GEMM body: C = A @ Bm^T (+bias), 128x128, BK=64 ---
template <typename OutT>
__device__ __forceinline__ void gemm_body(
    const __hip_bfloat16* __restrict__ A, const __hip_bfloat16* __restrict__ Bm,
    const float* __restrict__ bias, OutT* __restrict__ C,
    int N, int m0, int n0, int brow,
    __hip_bfloat16* As, __hip_bfloat16* Bs)
{
    const int t = threadIdx.x, lane = t & 63, w = t >> 6;
    const int l15 = lane & 15, g = lane >> 4;
    const int wr = w >> 1, wc = w & 1;

    f32x4 acc[4][4] = {};

    for (int k0 = 0; k0 < 1024; k0 += 64) {
        __syncthreads();
        #pragma unroll
        for (int it = 0; it < 4; ++it) {
            const int chunk = it * 256 + w * 64 + lane;
            const int row = chunk >> 3, c = chunk & 7;
            gl_lds16(A  + (size_t)(m0 + row) * 1024 + k0 + c * 8, (char*)As + chunk * 16);
            gl_lds16(Bm + (size_t)(n0 + row) * 1024 + k0 + c * 8, (char*)Bs + chunk * 16);
        }
        __syncthreads();
        #pragma unroll
        for (int kk = 0; kk < 64; kk += 32) {
            bf16x8 af[4], bfr[4];
            #pragma unroll
            for (int i = 0; i < 4; ++i)
                af[i] = *(const bf16x8*)((const char*)As + (wr * 64 + i * 16 + l15) * 128 + kk * 2 + g * 16);
            #pragma unroll
            for (int j = 0; j < 4; ++j)
                bfr[j] = *(const bf16x8*)((const char*)Bs + (wc * 64 + j * 16 + l15) * 128 + kk * 2 + g * 16);
            #pragma unroll
            for (int i = 0; i < 4; ++i)
                #pragma unroll
                for (int j = 0; j < 4; ++j)
                    acc[i][j] = __builtin_amdgcn_mfma_f32_16x16x32_bf16(af[i], bfr[j], acc[i][j], 0, 0, 0);
        }
    }

    #pragma unroll
    for (int i = 0; i < 4; ++i) {
        const int m = m0 + wr * 64 + i * 16 + g * 4;
        #pragma unroll
        for (int j = 0; j < 4; ++j) {
            const int n = n0 + wc * 64 + j * 16 + l15;
            const float bc = brow ? 0.f : bias[n];
            #pragma unroll
            for (int r = 0; r < 4; ++r) {
                const float v = acc[i][j][r] + (brow ? bias[m + r] : bc);
                C[(size_t)(m + r) * N + n] = (OutT)v;
            }
        }
    }
}

// fused Q/K/V projections: grid (8, 32, 3)
__global__ __launch_bounds__(256) void qkv_gemm(
    const __hip_bfloat16* __restrict__ qin, const __hip_bfloat16* __restrict__ kin,
    const __hip_bfloat16* __restrict__ vin,
    const __hip_bfloat16* __restrict__ Wqb, const __hip_bfloat16* __restrict__ Wkb,
    const __hip_bfloat16* __restrict__ Wvb,
    const float* __restrict__ bq, const float* __restrict__ bk, const float* __restrict__ bv,
    __hip_bfloat16* __restrict__ qbuf, __hip_bfloat16* __restrict__ kbuf,
    __hip_bfloat16* __restrict__ vtb)
{
    __shared__ __align__(16) __hip_bfloat16 As[128 * 64];
    __shared__ __align__(16) __hip_bfloat16 Bs[128 * 64];
    const int z = blockIdx.z;
    if (z == 0)
        gemm_body(qin, Wqb, bq, qbuf, 1024, blockIdx.y * 128, blockIdx.x * 128, 0, As, Bs);
    else if (z == 1)
        gemm_body(kin, Wkb, bk, kbuf, 1024, blockIdx.y * 128, blockIdx.x * 128, 0, As, Bs);
    else  // V^T = Wv @ vin^T, bias per output ROW (d)
        gemm_body(Wvb, vin, bv, vtb, 4096, blockIdx.x * 128, blockIdx.y * 128, 1, As, Bs);
}

// out projection (fp32 out): grid (8, 32)
__global__ __launch_bounds__(256) void out_gemm(
    const __hip_bfloat16* __restrict__ A, const __hip_bfloat16* __restrict__ Bm,
    const float* __restrict__ bias, float* __restrict__ C)
{
    __shared__ __align__(16) __hip_bfloat16 As[128 * 64];
    __shared__ __align__(16) __hip_bfloat16 Bs[128 * 64];
    gemm_body(A, Bm, bias, C, 1024, blockIdx.y * 128, blockIdx.x * 128, 0, As, Bs);
}

// ---------------- MFMA flash attention (swapped QK^T, fixed-C softmax) ------
// 1024 blocks x 256 threads (4 waves); block = 64 q-rows of one (b,h).
// Q in registers; K/V single-buffered LDS; 24 KB LDS -> 6 blocks/CU.
// XCD swizzle: bh pinned so each XCD's L2 holds 4 heads' K/V (2 MB < 4 MB).
__global__ __launch_bounds__(256, 6) void attn_mfma(
    const __hip_bfloat16* __restrict__ qb,   // [4096][1024] plain Q projection
    const __hip_bfloat16* __restrict__ kb,   // [4096][1024] plain K projection
    const __hip_bfloat16* __restrict__ vt,   // [1024][4096] V^T
    const unsigned long long* __restrict__ mbits,  // [2048][32]
    __hip_bfloat16* __restrict__ ctx)        // [4096][1024]
{
    __shared__ __align__(16) __hip_bfloat16 Ks[64 * 64];      // 8 KB
    __shared__ __align__(16) __hip_bfloat16 Vs[64 * 64];      // 8 KB
    __shared__ __align__(16) __hip_bfloat16 Pb[4][16 * 64];   // 8 KB

    const int t = threadIdx.x, lane = t & 63, w = t >> 6;
    const int l15 = lane & 15, g = lane >> 4;

    // XCD-pinning swizzle: bid%8 selects XCD; give it 4 whole heads
    const int bid = blockIdx.x;
    const int xcd = bid & 7, i = bid >> 3;          // i: 0..127
    const int bh = xcd * 4 + (i >> 5), qt = i & 31; // 4 bh per XCD, 32 q-tiles each
    const int b = bh >> 4, a = bh & 15;
    const int q0 = qt * 64;
    const int hq = q0 >> 7;                  // original column block of Q proj

    constexpr float SC_LOG2E = 0.18033688011112042f;   // 0.125*log2(e)
    constexpr float OFFC     = -17.312340490667561f;   // -12*log2(e)
    constexpr float MASKB    = -1.0e9f;

    // ---- Q fragments straight to registers (loop-invariant B-operand) ----
    const int qrow = w * 16 + l15;           // wave-local q row 0..63
    const int s = ((q0 & 64) + qrow) * 16 + a;   // inverse double-split row
    bf16x8 qreg[2];
    #pragma unroll
    for (int half = 0; half < 2; ++half)
        qreg[half] = *(const bf16x8*)&qb[(size_t)(b * 2048 + s) * 1024 + hq * 64 + (half * 4 + g) * 8];

    f32x4 accd[4] = {};
    float l_r = 0.f;
    const int qg = q0 + qrow;                // attention row 0..2047

    for (int kt = 0; kt < 32; ++kt) {
        __syncthreads();                     // prev tile fully consumed (WAR)
        #pragma unroll
        for (int it = 0; it < 2; ++it) {     // stage K and V tiles (2+2 chunks)
            const int c = it * 256 + t;      // 0..511
            const int row = c >> 3, cc = c & 7;
            const int cs = cc ^ (row & 7);
            gl_lds16(kb + (size_t)(b * 2048 + kt * 64 + row) * 1024 + a * 64 + cs * 8,
                     (char*)Ks + c * 16);
            gl_lds16(vt + (size_t)(a * 64 + row) * 4096 + b * 2048 + kt * 64 + cs * 8,
                     (char*)Vs + c * 16);
        }
        const uint2 mw = *(const uint2*)&mbits[(size_t)qg * 32 + kt];
        __syncthreads();                     // staged tile visible (vmcnt drained)

        // ---- S^T = K Q^T : lane owns q-col l15, kk = 16nf+4g+r ----
        f32x4 sf[4] = {};
        #pragma unroll
        for (int half = 0; half < 2; ++half) {
            const int kc = half * 4 + g;
            #pragma unroll
            for (int nf = 0; nf < 4; ++nf) {
                const int krow = nf * 16 + l15;
                const bf16x8 kf = *(const bf16x8*)((const char*)Ks + krow * 128 + ((kc ^ (krow & 7)) << 4));
                sf[nf] = __builtin_amdgcn_mfma_f32_16x16x32_bf16(kf, qreg[half], sf[nf], 0, 0, 0);
            }
        }

        // ---- fixed-C softmax: p = exp2(s*0.125*log2e - 12*log2e), mask -> 0
        float psum = 0.f;
        #pragma unroll
        for (int nf = 0; nf < 4; ++nf) {
            const unsigned word = (nf & 2) ? mw.y : mw.x;
            const int bsh = ((nf & 1) << 4) + (g << 2);
            float pr[4];
            #pragma unroll
            for (int r = 0; r < 4; ++r) {
                const bool msk = (word >> (bsh + r)) & 1u;
                pr[r] = exp2f(fmaf(sf[nf][r], SC_LOG2E, msk ? MASKB : OFFC));
            }
            psum += (pr[0] + pr[1]) + (pr[2] + pr[3]);
            __hip_bfloat16 h0 = __float2bfloat16(pr[0]), h1 = __float2bfloat16(pr[1]);
            __hip_bfloat16 h2 = __float2bfloat16(pr[2]), h3 = __float2bfloat16(pr[3]);
            const unsigned w0 = (unsigned)*(unsigned short*)&h0 | ((unsigned)*(unsigned short*)&h1 << 16);
            const unsigned w1 = (unsigned)*(unsigned short*)&h2 | ((unsigned)*(unsigned short*)&h3 << 16);
            // P row q=l15 (wave-private), kk pair base 16nf+4g: byte 32nf+8g+{0,4}
            char* pb = (char*)Pb + w * 2048 + l15 * 128 +
                       (((2 * nf + (g >> 1)) ^ (l15 & 7)) << 4) + ((g & 1) << 3);
            *(uint2*)pb = make_uint2(w0, w1);
        }
        psum += __shfl_xor(psum, 16);
        psum += __shfl_xor(psum, 32);
        l_r += psum;

        // ---- acc += P V : A-frag = P row l15, kk chunk 8g.. (swz b128 read)
        #pragma unroll
        for (int jj = 0; jj < 2; ++jj) {
            const bf16x8 pa = *(const bf16x8*)((const char*)Pb + w * 2048 + l15 * 128 +
                                               (((4 * jj + g) ^ (l15 & 7)) << 4));
            #pragma unroll
            for (int df = 0; df < 4; ++df) {
                const int vrow = df * 16 + l15;
                const bf16x8 vf = *(const bf16x8*)((const char*)Vs + vrow * 128 +
                                                   (((4 * jj + g) ^ (vrow & 7)) << 4));
                accd[df] = __builtin_amdgcn_mfma_f32_16x16x32_bf16(pa, vf, accd[df], 0, 0, 0);
            }
        }
    }

    // epilogue: accd row m = g*4+r (q), col d = df*16+l15; l lives at lane (4g+r)
    #pragma unroll
    for (int r = 0; r < 4; ++r) {
        const float lq = __shfl(l_r, (g << 2) + r);
        const float inv = 1.0f / lq;
        const int q = q0 + w * 16 + (g << 2) + r;
        #pragma unroll
        for (int df = 0; df < 4; ++df)
            ctx[(size_t)(b * 2048 + q) * 1024 + (a << 6) + df * 16 + l15] =
                __float2bfloat16(accd[df][r] * inv);
    }
}

extern "C" void kernel_launch(void* const* d_in, const int* in_sizes, int n_in,
                              void* d_out, int out_size, void* d_ws, size_t ws_size,
                              hipStream_t stream)
{
    const float* queries = (const float*)d_in[0];
    const float* keys    = (const float*)d_in[1];
    const float* values  = (const float*)d_in[2];
    const int*   mask    = (const int*)  d_in[3];
    const float* Wq = (const float*)d_in[4];
    const float* bq = (const float*)d_in[5];
    const float* Wk = (const float*)d_in[6];
    const float* bk = (const float*)d_in[7];
    const float* Wv = (const float*)d_in[8];
    const float* bv = (const float*)d_in[9];
    const float* Wo = (const float*)d_in[10];
    const float* bo = (const float*)d_in[11];

    const size_t NM = (size_t)4096 * 1024;
    const size_t NW = (size_t)1024 * 1024;
    __hip_bfloat16* p = (__hip_bfloat16*)d_ws;
    __hip_bfloat16* qin = p;  p += NM;
    __hip_bfloat16* kin = p;  p += NM;
    __hip_bfloat16* vin = p;  p += NM;
    __hip_bfloat16* Wqb = p;  p += NW;
    __hip_bfloat16* Wkb = p;  p += NW;
    __hip_bfloat16* Wvb = p;  p += NW;
    __hip_bfloat16* Wob = p;  p += NW;
    __hip_bfloat16* qbuf = p; p += NM;
    __hip_bfloat16* kbuf = p; p += NM;
    __hip_bfloat16* vtb  = p; p += NM;
    unsigned long long* mbits = (unsigned long long*)p;  // 512 KB
    __hip_bfloat16* ctxb = qin;              // alias: qin dead after qkv_gemm

    convert_all<<<dim3(8192), dim3(256), 0, stream>>>(
        queries, keys, values, Wq, Wk, Wv, Wo,
        qin, kin, vin, Wqb, Wkb, Wvb, Wob);
    packmask<<<dim3(16384), dim3(256), 0, stream>>>(mask, mbits);

    qkv_gemm<<<dim3(8, 32, 3), dim3(256), 0, stream>>>(
        qin, kin, vin, Wqb, Wkb, Wvb, bq, bk, bv, qbuf, kbuf, vtb);

    attn_mfma<<<dim3(1024), dim3(256), 0, stream>>>(qbuf, kbuf, vtb, mbits, ctxb);

    out_gemm<<<dim3(8, 32), dim3(256), 0, stream>>>(ctxb, Wob, bo, (float*)d_out);
}